// Round 1
// 133.868 us; speedup vs baseline: 1.0756x; 1.0756x over previous
//
#include <hip/hip_runtime.h>

#define BB 256
#define TT 1024
#define VV 64
#define LL 64
#define LOG2E 1.4426950408889634f
#define LN2   0.6931471805599453f

__device__ __forceinline__ int   f2i(float x) { return __float_as_int(x); }
__device__ __forceinline__ float i2f(int x)   { return __int_as_float(x); }

// lgkm-only barrier: orders LDS producer->consumer WITHOUT draining vmcnt,
// so the async global->LDS prefetch queue survives across windows (T4).
__device__ __forceinline__ void barrier_lds() {
  asm volatile("s_waitcnt lgkmcnt(0)" ::: "memory");
  __builtin_amdgcn_s_barrier();
}

// wave-wide max of non-negative values (0 identity), result broadcast
__device__ __forceinline__ float wave_max63(float x) {
  x = fmaxf(x, i2f(__builtin_amdgcn_update_dpp(0, f2i(x), 0x111, 0xF, 0xF, true)));
  x = fmaxf(x, i2f(__builtin_amdgcn_update_dpp(0, f2i(x), 0x112, 0xF, 0xF, true)));
  x = fmaxf(x, i2f(__builtin_amdgcn_update_dpp(0, f2i(x), 0x114, 0xF, 0xF, true)));
  x = fmaxf(x, i2f(__builtin_amdgcn_update_dpp(0, f2i(x), 0x118, 0xF, 0xF, true)));
  x = fmaxf(x, i2f(__builtin_amdgcn_update_dpp(0, f2i(x), 0x142, 0xF, 0xF, true)));
  x = fmaxf(x, i2f(__builtin_amdgcn_update_dpp(0, f2i(x), 0x143, 0xF, 0xF, true)));
  return i2f(__builtin_amdgcn_readlane(f2i(x), 63));
}

// async 16B/lane global->LDS: LDS dest is wave-uniform base + lane*16,
// global src is per-lane (natural row-major contiguous here).
__device__ __forceinline__ void gload16(const float* g, float* l) {
  __builtin_amdgcn_global_load_lds(
      (const __attribute__((address_space(1))) unsigned int*)g,
      (__attribute__((address_space(3))) unsigned int*)l, 16, 0, 0);
}

// ---------- Fused kernel: block b = batch element b, 5 waves ----------
// Waves 1-4 (producers): per window each owns 4 rows. They issue ONE async
// global_load_lds (raw logits, depth-4 ring, counted vmcnt(2) waits — loads
// stay in flight across 3 windows, covering ~900cy HBM latency), then read
// their quarter-rows back (ds_read_b128), exp, and do the row-LSE with a
// VALU-only DPP row_shr reduce (no ds_swizzle on the critical path).
// Wave 0 (consumer): reads raw c (blank) + g (label) per row, exps them
// itself (trans pipe fills DP-chain bubbles), linear-space DP with renorm
// to 2^60 every 16 steps (R9-validated cadence, unchanged). Loop exits at
// ceil(len/16); fully-active windows use unmasked steps (act is uniform).
extern "C" __global__ void __launch_bounds__(320, 1)
ctc_fused(const int* __restrict__ labels, const float* __restrict__ logits,
          const int* __restrict__ mask, float* __restrict__ out) {
  __shared__ __align__(16) float rawb[4][16][VV];   // 16 KB raw-logit ring
  __shared__ float lsePart[4];
  const int b = blockIdx.x;
  const int tid = threadIdx.x;
  const int lane = tid & 63;
  const int wv = tid >> 6;

  const float* lg = logits + (size_t)b * TT * VV;

  // every wave computes len (redundant, preamble-only)
  int lsum = 0;
  const int* mrow = mask + b * TT;
#pragma unroll
  for (int k = 0; k < TT / 64; ++k) lsum += mrow[lane + (k << 6)];
#pragma unroll
  for (int off = 32; off; off >>= 1) lsum += __shfl_xor(lsum, off);
  int len = __builtin_amdgcn_readfirstlane(lsum);
  len = len < 1 ? 1 : (len > TT ? TT : len);
  const int nwin = (len + 15) >> 4;      // windows actually needed

  // wave-0-only DP state
  int lab = 0, lab_len = 0;
  float sk = 0.0f;
  float A0 = 0.0f, A1 = 0.0f, A2 = 0.0f;
  int ctot = 0;
  if (wv == 0) {
    lab = labels[b * LL + lane] & 63;             // label for state 2*lane+1
    lab_len = (int)__popcll(__ballot(lab != 0));
    const int plab = __builtin_amdgcn_update_dpp(0, lab, 0x138, 0xF, 0xF, false);
    sk = (lab != 0 && lab != plab) ? 1.0f : 0.0f; // allow_skip
    A0 = (lane == 0) ? 1.0f : 0.0f;               // t=0 runs as a normal step
    __builtin_amdgcn_s_setprio(1);                // consumer is critical path
  }

  // producer geometry: wave wv owns window-rows (wv-1)*4 + rg, rg = lane>>4
  const int rg = lane >> 4;
  const int colv = (lane & 15) << 2;
  const int r0 = ((wv - 1) << 2) + rg;
  float acc = 0.0f;

#define GLOAD(WN) gload16(lg + (size_t)(((((WN) << 4) + ((wv - 1) << 2)) << 6) + (lane << 2)), \
                          &rawb[(WN) & 3][(wv - 1) << 2][0])

  // renorm to 2^60 (R9-validated): flush floor ~186 log2 below running max,
  // overflow headroom +67 log2 per 16-step window.
#define RENORM() { \
    const float mxv = wave_max63(fmaxf(fmaxf(A0, A1), A2)); \
    const int eb = (f2i(mxv) >> 23) & 255; \
    int kk = (eb > 0 && eb < 255) ? (187 - eb) : 0; \
    kk = kk > 126 ? 126 : (kk < -126 ? -126 : kk); \
    ctot += kk; \
    const float sc = i2f((127 + kk) << 23); \
    A0 *= sc; A1 *= sc; A2 *= sc; \
  }

#define STEPU(U) { \
    const float A1p = i2f(__builtin_amdgcn_update_dpp(0, f2i(A1), 0x138, 0xF, 0xF, false)); \
    const float nA0 = c##U * (A0 + A1p); \
    const float nA1 = g##U * fmaf(sk, A1p, A0 + A1); \
    A2 = c##U * (A2 + A1); \
    A0 = nA0; A1 = nA1; \
  }

#define STEPM(U) { \
    const float A1p = i2f(__builtin_amdgcn_update_dpp(0, f2i(A1), 0x138, 0xF, 0xF, false)); \
    const float nA0 = c##U * (A0 + A1p); \
    const float nA1 = g##U * fmaf(sk, A1p, A0 + A1); \
    const float nA2 = c##U * (A2 + A1); \
    const bool act = (tbase + (U)) < len; \
    A0 = act ? nA0 : A0; A1 = act ? nA1 : A1; A2 = act ? nA2 : A2; \
  }

  // prologue: producers queue windows 0,1,2 (depth-4 ring, 3 in flight)
  if (wv != 0) { GLOAD(0); GLOAD(1); GLOAD(2); }

  for (int w = 0; w < nwin; ++w) {
    if (wv != 0) {
      // counted wait: window w's DMA landed; newer loads stay in flight.
      if (w < 62)       asm volatile("s_waitcnt vmcnt(2)" ::: "memory");
      else if (w == 62) asm volatile("s_waitcnt vmcnt(1)" ::: "memory");
      else              asm volatile("s_waitcnt vmcnt(0)" ::: "memory");
    }
    barrier_lds();   // consumer may now read window w; slot (w+3)&3 is free
    if (wv != 0) {
      const int wn = w + 3;
      if (wn < 64) GLOAD(wn);            // overwrites slot consumed at w-1
      // ---- row-LSE for window w, own 4 rows ----
      const float4 rv = *(const float4*)&rawb[w & 3][r0][colv];
      const float e0 = __builtin_amdgcn_exp2f(rv.x * LOG2E);
      const float e1 = __builtin_amdgcn_exp2f(rv.y * LOG2E);
      const float e2 = __builtin_amdgcn_exp2f(rv.z * LOG2E);
      const float e3 = __builtin_amdgcn_exp2f(rv.w * LOG2E);
      float s = (e0 + e1) + (e2 + e3);
      // VALU-only 16-lane reduce (same balanced tree as the old xor
      // butterfly -> bit-identical sum); result lands in lane 15 of group
      s += i2f(__builtin_amdgcn_update_dpp(0, f2i(s), 0x111, 0xF, 0xF, true));
      s += i2f(__builtin_amdgcn_update_dpp(0, f2i(s), 0x112, 0xF, 0xF, true));
      s += i2f(__builtin_amdgcn_update_dpp(0, f2i(s), 0x114, 0xF, 0xF, true));
      s += i2f(__builtin_amdgcn_update_dpp(0, f2i(s), 0x118, 0xF, 0xF, true));
      if ((lane & 15) == 15 && (((w << 4) + r0) < len)) acc += __logf(s);
    } else {
      // ---- wave 0: consume window w ----
      const float* rb = &rawb[w & 3][0][0];
      float c0, c1, c2, c3, c4, c5, c6, c7, c8, c9, c10, c11, c12, c13, c14, c15;
      float g0, g1, g2, g3, g4, g5, g6, g7, g8, g9, g10, g11, g12, g13, g14, g15;
#define RD(U) c##U = rb[(U) << 6]; g##U = rb[((U) << 6) + lab];
      RD(0)  RD(1)  RD(2)  RD(3)  RD(4)  RD(5)  RD(6)  RD(7)
      RD(8)  RD(9)  RD(10) RD(11) RD(12) RD(13) RD(14) RD(15)
#undef RD
      // pin: LDS reads cannot sink below this point (issue early, wait late)
      asm volatile("" ::: "memory");
#define EX(U) c##U = __builtin_amdgcn_exp2f(c##U * LOG2E); \
              g##U = __builtin_amdgcn_exp2f(g##U * LOG2E);
      EX(0)  EX(1)  EX(2)  EX(3)  EX(4)  EX(5)  EX(6)  EX(7)
      EX(8)  EX(9)  EX(10) EX(11) EX(12) EX(13) EX(14) EX(15)
#undef EX
      RENORM()
      const int tbase = w << 4;
      if (tbase + 16 <= len) {   // whole window active: no cndmask on chain
        STEPU(0)  STEPU(1)  STEPU(2)  STEPU(3)  STEPU(4)  STEPU(5)  STEPU(6)  STEPU(7)
        STEPU(8)  STEPU(9)  STEPU(10) STEPU(11) STEPU(12) STEPU(13) STEPU(14) STEPU(15)
      } else {                   // boundary window
        STEPM(0)  STEPM(1)  STEPM(2)  STEPM(3)  STEPM(4)  STEPM(5)  STEPM(6)  STEPM(7)
        STEPM(8)  STEPM(9)  STEPM(10) STEPM(11) STEPM(12) STEPM(13) STEPM(14) STEPM(15)
      }
    }
  }

  // producers publish LSE partials; one more uniform barrier
  if (wv != 0) {
    // drain stray prefetches before LDS could be deallocated at wave exit
    asm volatile("s_waitcnt vmcnt(0)" ::: "memory");
    float a = ((lane & 15) == 15) ? acc : 0.0f;
    a += __shfl_xor(a, 16);
    a += __shfl_xor(a, 32);
    if (lane == 63) lsePart[wv - 1] = a;
  }
  barrier_lds();

  if (wv == 0) {
    float ae, ae1;
    if (lab_len >= LL) {            // e = 128
      ae  = i2f(__builtin_amdgcn_readlane(f2i(A2), 63));
      ae1 = i2f(__builtin_amdgcn_readlane(f2i(A1), 63));
    } else if (lab_len >= 1) {      // e = 2*lab_len
      ae  = i2f(__builtin_amdgcn_readlane(f2i(A0), lab_len));
      ae1 = i2f(__builtin_amdgcn_readlane(f2i(A1), lab_len - 1));
    } else {
      ae  = i2f(__builtin_amdgcn_readlane(f2i(A0), 0));
      ae1 = ae;
    }
    const float se = ae + ae1;      // linear-space logaddexp
    float loss = ((lsePart[0] + lsePart[1]) + (lsePart[2] + lsePart[3]))
               - LN2 * (__builtin_amdgcn_logf(se) - (float)ctot);
    if (lab_len > len) loss = 0.0f; // feasibility mask
    if (lane == 0) atomicAdd(out, loss * (1.0f / 256.0f));
  }
#undef STEPM
#undef STEPU
#undef RENORM
#undef GLOAD
}

extern "C" void kernel_launch(void* const* d_in, const int* in_sizes, int n_in,
                              void* d_out, int out_size, void* d_ws, size_t ws_size,
                              hipStream_t stream) {
  (void)in_sizes; (void)n_in; (void)out_size; (void)d_ws; (void)ws_size;
  hipMemsetAsync(d_out, 0, sizeof(float), stream);   // d_out is poisoned 0xAA
  ctc_fused<<<dim3(BB), dim3(320), 0, stream>>>(
      (const int*)d_in[0], (const float*)d_in[1], (const int*)d_in[2], (float*)d_out);
}